// Round 11
// baseline (88.233 us; speedup 1.0000x reference)
//
#include <hip/hip_runtime.h>

// HardMoE classifier: B=131072, D=768, E=6, L=2 == skinny GEMM 131072x30x768.
// R11: R9/R10 core (channel-uniform 256B X staging, MFMA 3-way-split gate,
//      pre-packed W) with W FRAGMENTS SERVED FROM BLOCK LDS instead of global:
//      the 48KB W image was being re-streamed per wave (4096 waves x 48KB =
//      196MB = 2.4 TB/s of read demand sharing the path with X's 5 TB/s ->
//      combined ~7.4 TB/s saturated the read-delivery ceiling). Now loaded
//      once per block (48 gload_lds), read via linear ds_read_b128 (free).
//      LDS 115.7KB -> 1 block/CU; X pipeline re-phased: each buffer's refill
//      issued a full compute phase before its counted vmcnt(8) wait.

#define BB 131072
#define DD 768
#define RPB 128             // rows per block = 4 waves x 32
#define NSUP 12             // K supers (4 x 16-k steps each)
#define SPAN 1040           // 1024B staged + 16B pad (bank-phase shift)
#define BUFO 8320           // 8 spans per buffer
#define WREG 16640          // per-wave LDS: 2 buffers
#define WTU (96 * 32 * 4)   // uints in packed W image (48 KB)

typedef __bf16 bf16x8 __attribute__((ext_vector_type(8)));
typedef float floatx16 __attribute__((ext_vector_type(16)));
typedef unsigned short ushortx8 __attribute__((ext_vector_type(8)));

#define GLOAD_LDS16(gsrc, ldst)                                                \
  __builtin_amdgcn_global_load_lds(                                            \
      (const __attribute__((address_space(1))) void*)(gsrc),                   \
      (__attribute__((address_space(3))) void*)(ldst), 16, 0, 0)

#define WAITV8 asm volatile("s_waitcnt vmcnt(8)" ::: "memory")
#define WAITV0 asm volatile("s_waitcnt vmcnt(0)" ::: "memory")

__device__ __forceinline__ unsigned bf16_rne(float x) {
  const unsigned u = __builtin_bit_cast(unsigned, x);
  return (u + 0x7fffu + ((u >> 16) & 1u)) >> 16;
}

// x -> hi + mid + lo (bf16-trunc each); gate recovers full f32 product.
__device__ __forceinline__ void cvt3(const float4& a, const float4& b,
                                     bf16x8& H, bf16x8& M, bf16x8& L) {
  const float v[8] = {a.x, a.y, a.z, a.w, b.x, b.y, b.z, b.w};
  ushortx8 h, m, l;
#pragma unroll
  for (int j = 0; j < 8; ++j) {
    const float x = v[j];
    const unsigned ub = __builtin_bit_cast(unsigned, x);
    const float rm = x - __builtin_bit_cast(float, ub & 0xffff0000u);
    const unsigned mb = __builtin_bit_cast(unsigned, rm);
    const float rl = rm - __builtin_bit_cast(float, mb & 0xffff0000u);
    h[j] = (unsigned short)(ub >> 16);
    m[j] = (unsigned short)(mb >> 16);
    l[j] = (unsigned short)(__builtin_bit_cast(unsigned, rl) >> 16);
  }
  H = __builtin_bit_cast(bf16x8, h);
  M = __builtin_bit_cast(bf16x8, m);
  L = __builtin_bit_cast(bf16x8, l);
}

// ---- kernel 1: pack W image into d_ws (R8/R9/R10-verified) ----
// cols 0-5 gate_hi, 6-11 gate_mid, 12-17 gate_lo, 18-29 expert(e*2+l), 30-31 0.
__global__ void pack_w_kernel(const float* __restrict__ gw,
                              const float* __restrict__ ew,
                              unsigned* __restrict__ wt) {
  const int u = blockIdx.x * 256 + threadIdx.x;
  if (u >= WTU) return;
  const int pair = u & 3;
  const int col  = (u >> 2) & 31;
  const int oct  = u >> 7;
  const int k0   = oct * 8 + pair * 2;
  unsigned val = 0;
  if (col < 18) {
    const int part = col / 6, j = col % 6;
    const float w0 = gw[j * DD + k0], w1 = gw[j * DD + k0 + 1];
    const unsigned u0 = __builtin_bit_cast(unsigned, w0);
    const unsigned u1 = __builtin_bit_cast(unsigned, w1);
    const float rm0 = w0 - __builtin_bit_cast(float, u0 & 0xffff0000u);
    const float rm1 = w1 - __builtin_bit_cast(float, u1 & 0xffff0000u);
    const unsigned m0 = __builtin_bit_cast(unsigned, rm0);
    const unsigned m1 = __builtin_bit_cast(unsigned, rm1);
    const float rl0 = rm0 - __builtin_bit_cast(float, m0 & 0xffff0000u);
    const float rl1 = rm1 - __builtin_bit_cast(float, m1 & 0xffff0000u);
    const unsigned l0 = __builtin_bit_cast(unsigned, rl0);
    const unsigned l1 = __builtin_bit_cast(unsigned, rl1);
    if (part == 0)      val = (u0 >> 16) | (u1 & 0xffff0000u);
    else if (part == 1) val = (m0 >> 16) | (m1 & 0xffff0000u);
    else                val = (l0 >> 16) | (l1 & 0xffff0000u);
  } else if (col < 30) {
    const int e = (col - 18) >> 1, l = (col - 18) & 1;
    val = bf16_rne(ew[(e * DD + k0) * 2 + l]) |
          (bf16_rne(ew[(e * DD + k0 + 1) * 2 + l]) << 16);
  }
  wt[u] = val;
}

// ---- kernel 2: main GEMM + argmax-select ----
__global__ __launch_bounds__(256, 1)
void HardMoE_kernel(const float* __restrict__ X,      // [B][768]
                    const unsigned* __restrict__ wtg, // packed W (d_ws)
                    const float* __restrict__ gb,     // [6]
                    const float* __restrict__ eb,     // [6][2]
                    float* __restrict__ out)          // [B][2]
{
  __shared__ char  xlds[4 * WREG];   // 66560 B; wave-private X regions
  __shared__ uint4 wlds[3072];       // 48 KB W image (block-shared)

  const int tid  = threadIdx.x;
  const int lane = tid & 63;
  const int w    = tid >> 6;
  const int mrow = lane & 31;       // A row in tile; B col
  const int koct = lane >> 5;       // k-octet of the 16-k step

  const int rbase = blockIdx.x * RPB + w * 32;
  char* wb = xlds + w * WREG;
  const float* Xw = X + (size_t)rbase * DD;
  // staging: inst i covers rows 4i..4i+3, 256B contiguous per row
  const int rowoff = (lane >> 4) * DD + (lane & 15) * 4;
  // read: lane's 32B of step t lives at rdoff + t*64
  const int rdoff  = (mrow >> 2) * SPAN + (mrow & 3) * 256 + koct * 32;

  // ---- one-time: W image -> block LDS (48 x 1KB gload_lds) ----
  {
    const char* ws = (const char*)wtg;
    char*       wd = (char*)wlds;
#pragma unroll
    for (int i = 0; i < 12; ++i) {
      const int off = (w * 12 + i) * 1024;
      GLOAD_LDS16(ws + off + lane * 16, wd + off);
    }
  }
  WAITV0;
  __syncthreads();                  // W visible; vmcnt clean for counting below

  auto stage = [&](int bufo, int q) {
#pragma unroll
    for (int i = 0; i < 8; ++i)
      GLOAD_LDS16(Xw + i * 4 * DD + q * 64 + rowoff,
                  wb + bufo + i * SPAN + lane * 16);
  };

  floatx16 acc;
#pragma unroll
  for (int j = 0; j < 16; ++j) acc[j] = 0.f;

  // wave-staggered q-walk: A takes evens-from-q0, B odds; union = all 12.
  int qa = 3 * w;                   // 0,3,6,9 for w=0..3
  int qb = qa + 1;
  stage(0, qa);
  stage(BUFO, qb);

  // W fragment for (q, t): wlds[q*256 + t*64 + lane]  (ds_read_b128, linear)
#define STEP3(bufo, WQ, t)                                                     \
  {                                                                            \
    const char* p = wb + (bufo) + rdoff + (t) * 64;                            \
    const float4 x0 = *(const float4*)p;                                       \
    const float4 x1 = *(const float4*)(p + 16);                                \
    bf16x8 xh, xm, xl;                                                         \
    cvt3(x0, x1, xh, xm, xl);                                                  \
    const bf16x8 bv = __builtin_bit_cast(bf16x8, (WQ)[(t) * 64]);              \
    acc = __builtin_amdgcn_mfma_f32_32x32x16_bf16(xh, bv, acc, 0, 0, 0);       \
    acc = __builtin_amdgcn_mfma_f32_32x32x16_bf16(xm, bv, acc, 0, 0, 0);       \
    acc = __builtin_amdgcn_mfma_f32_32x32x16_bf16(xl, bv, acc, 0, 0, 0);       \
  }

#pragma unroll 1
  for (int p = 0; p < 6; ++p) {
    WAITV8;                           // stageA(p) landed; stageB(p) in flight
    {
      const uint4* wqa = wlds + qa * 256 + lane;
      STEP3(0, wqa, 0) STEP3(0, wqa, 1) STEP3(0, wqa, 2) STEP3(0, wqa, 3)
    }
    if (p < 5) {                      // refill A a full phase before its wait
      qa += 2; if (qa >= NSUP) qa -= NSUP;
      stage(0, qa);
    }
    if (p < 5) { WAITV8; } else { WAITV0; }   // stageB(p) landed
    {
      const uint4* wqb = wlds + qb * 256 + lane;
      STEP3(BUFO, wqb, 0) STEP3(BUFO, wqb, 1)
      STEP3(BUFO, wqb, 2) STEP3(BUFO, wqb, 3)
    }
    if (p < 5) {
      qb += 2; if (qb >= NSUP) qb -= NSUP;
      stage(BUFO, qb);
    }
  }
#undef STEP3

  // ---- epilogue (R7-R10 verified): C col=lane&31, row=(reg&3)+8*(reg>>2)+4*koct
  float* cw = (float*)(xlds + w * WREG);  // reuse wave's own X region
#pragma unroll
  for (int reg = 0; reg < 16; ++reg) {
    const int r = (reg & 3) + 8 * (reg >> 2) + 4 * koct;
    const int byteoff = r * 128 + ((mrow * 4) ^ ((r & 7) << 4));
    *(float*)((char*)cw + byteoff) = acc[reg];
  }
  if (lane < 32) {
    const int r = lane;
    float cv[32];
#pragma unroll
    for (int j = 0; j < 8; ++j) {
      const float4 qv = *(const float4*)((const char*)cw + r * 128 +
                                         ((j * 16) ^ ((r & 7) << 4)));
      cv[4 * j] = qv.x; cv[4 * j + 1] = qv.y;
      cv[4 * j + 2] = qv.z; cv[4 * j + 3] = qv.w;
    }
    float g[6];
#pragma unroll
    for (int c = 0; c < 6; ++c) g[c] = cv[c] + cv[6 + c] + cv[12 + c] + gb[c];
    int best = 0; float bv = g[0];
#pragma unroll
    for (int c = 1; c < 6; ++c) { if (g[c] > bv) { bv = g[c]; best = c; } }
    float ebv[12];
#pragma unroll
    for (int i = 0; i < 12; ++i) ebv[i] = eb[i];
    float o0 = cv[18] + ebv[0], o1 = cv[19] + ebv[1];
#pragma unroll
    for (int e = 1; e < 6; ++e) {
      const bool s = (best == e);
      o0 = s ? cv[18 + 2 * e] + ebv[2 * e]     : o0;
      o1 = s ? cv[19 + 2 * e] + ebv[2 * e + 1] : o1;
    }
    ((float2*)out)[rbase + r] = make_float2(o0, o1);
  }
}

extern "C" void kernel_launch(void* const* d_in, const int* in_sizes, int n_in,
                              void* d_out, int out_size, void* d_ws, size_t ws_size,
                              hipStream_t stream) {
  (void)in_sizes; (void)n_in; (void)ws_size; (void)out_size;
  const float* X  = (const float*)d_in[0];
  const float* gw = (const float*)d_in[1];
  const float* gb = (const float*)d_in[2];
  const float* ew = (const float*)d_in[3];
  const float* eb = (const float*)d_in[4];
  float* out = (float*)d_out;
  unsigned* wt = (unsigned*)d_ws;   // 48 KB

  pack_w_kernel<<<WTU / 256, 256, 0, stream>>>(gw, ew, wt);
  HardMoE_kernel<<<BB / RPB, 256, 0, stream>>>(X, wt, gb, eb, out);
}

// Round 12
// 84.460 us; speedup vs baseline: 1.0447x; 1.0447x over previous
//
#include <hip/hip_runtime.h>

// HardMoE classifier: B=131072, D=768, E=6, L=2 == skinny GEMM 131072x30x768.
// R12: contiguity experiment. 16x16x32 MFMA (16-row wave tile) so each staged
//      buffer is 16 rows x 512B -> every global_load_lds covers 2 rows x 512B
//      CONTIGUOUS (vs R9-R11's 4 rows x 256B). 8 waves/CU preserved
//      (64KB LDS/block, 2 blocks/CU). W from L2 (R10-proven), prefetched
//      1 chunk ahead; counted vmcnt(16) = 8 stage + 8 W in flight.
//      Numerics identical to R7-R11: 3-way-split f32-exact gate (no argmax
//      flips), exact-X x rne-bf16-W experts (absmax 0.015625).

#define BB 131072
#define DD 768
#define RPW 16              // rows per wave tile
#define RPB 64              // rows per block (4 waves)
#define NCH 6               // 512-B K-chunks per row (each = 4 K32 steps)
#define WTU4 3072           // uint4 count of W image (48 KB)

typedef __bf16 bf16x8 __attribute__((ext_vector_type(8)));
typedef float floatx4 __attribute__((ext_vector_type(4)));
typedef unsigned short ushortx8 __attribute__((ext_vector_type(8)));

#define GLOAD_LDS16(gsrc, ldst)                                                \
  __builtin_amdgcn_global_load_lds(                                            \
      (const __attribute__((address_space(1))) void*)(gsrc),                   \
      (__attribute__((address_space(3))) void*)(ldst), 16, 0, 0)

#define WAITV16 asm volatile("s_waitcnt vmcnt(16)" ::: "memory")
#define WAITV0  asm volatile("s_waitcnt vmcnt(0)" ::: "memory")
#define CBAR    asm volatile("" ::: "memory")

__device__ __forceinline__ unsigned bf16_rne(float x) {
  const unsigned u = __builtin_bit_cast(unsigned, x);
  return (u + 0x7fffu + ((u >> 16) & 1u)) >> 16;
}

// gate weight 3-way split part (truncation; hi+mid+lo reconstructs f32)
__device__ __forceinline__ unsigned gate_part(float x, int part) {
  const unsigned ub = __builtin_bit_cast(unsigned, x);
  const float rm = x - __builtin_bit_cast(float, ub & 0xffff0000u);
  const unsigned mb = __builtin_bit_cast(unsigned, rm);
  const float rl = rm - __builtin_bit_cast(float, mb & 0xffff0000u);
  const unsigned lb = __builtin_bit_cast(unsigned, rl);
  return part == 0 ? (ub >> 16) : part == 1 ? (mb >> 16) : (lb >> 16);
}

// x -> hi + mid + lo (bf16-trunc each); gate recovers full f32 product.
__device__ __forceinline__ void cvt3(const float4& a, const float4& b,
                                     bf16x8& H, bf16x8& M, bf16x8& L) {
  const float v[8] = {a.x, a.y, a.z, a.w, b.x, b.y, b.z, b.w};
  ushortx8 h, m, l;
#pragma unroll
  for (int j = 0; j < 8; ++j) {
    const float x = v[j];
    const unsigned ub = __builtin_bit_cast(unsigned, x);
    const float rm = x - __builtin_bit_cast(float, ub & 0xffff0000u);
    const unsigned mb = __builtin_bit_cast(unsigned, rm);
    const float rl = rm - __builtin_bit_cast(float, mb & 0xffff0000u);
    h[j] = (unsigned short)(ub >> 16);
    m[j] = (unsigned short)(mb >> 16);
    l[j] = (unsigned short)(__builtin_bit_cast(unsigned, rl) >> 16);
  }
  H = __builtin_bit_cast(bf16x8, h);
  M = __builtin_bit_cast(bf16x8, m);
  L = __builtin_bit_cast(bf16x8, l);
}

// ---- kernel 1: pack W image for 16x16x32 B-fragments ----
// Logical cols (0..31): 0-5 gate_hi, 6-11 gate_mid, 12-17 gate_lo,
// 18-29 expert(e*2+l), 30-31 zero. B-frag: col=lane&15 (+16*half),
// koct=lane>>4, 8 contiguous k. uint4 u = index ((step*2+half)*64 + lane).
__global__ void pack_w_kernel(const float* __restrict__ gw,
                              const float* __restrict__ ew,
                              uint4* __restrict__ wt) {
  const int u = blockIdx.x * 256 + threadIdx.x;
  if (u >= WTU4) return;
  const int l = u & 63;
  const int h = (u >> 6) & 1;
  const int s = u >> 7;             // K32 step 0..23
  const int col = h * 16 + (l & 15);
  const int k0  = s * 32 + (l >> 4) * 8;
  unsigned r[4];
#pragma unroll
  for (int j2 = 0; j2 < 4; ++j2) {
    const int ka = k0 + 2 * j2, kb = ka + 1;
    unsigned lo = 0, hi = 0;
    if (col < 18) {
      const int part = col / 6, gj = col % 6;
      lo = gate_part(gw[gj * DD + ka], part);
      hi = gate_part(gw[gj * DD + kb], part);
    } else if (col < 30) {
      const int e = (col - 18) >> 1, lb = (col - 18) & 1;
      lo = bf16_rne(ew[(e * DD + ka) * 2 + lb]);
      hi = bf16_rne(ew[(e * DD + kb) * 2 + lb]);
    }
    r[j2] = lo | (hi << 16);
  }
  wt[u] = make_uint4(r[0], r[1], r[2], r[3]);
}

// ---- kernel 2: main GEMM + argmax-select ----
__global__ __launch_bounds__(256, 2)
void HardMoE_kernel(const float* __restrict__ X,    // [B][768]
                    const uint4* __restrict__ wtv,  // packed W (d_ws)
                    const float* __restrict__ gb,   // [6]
                    const float* __restrict__ eb,   // [6][2]
                    float* __restrict__ out)        // [B][2]
{
  __shared__ char xlds[4][2][8192];  // [wave][buf][16 rows x 512B], 64 KB

  const int tid  = threadIdx.x;
  const int lane = tid & 63;
  const int w    = tid >> 6;
  const int rbase = blockIdx.x * RPB + w * RPW;
  const float* Xw = X + (size_t)rbase * DD;

  // stage chunk q (512B per row) into buf: 8 insts x 1KB, 2 rows each,
  // CONTIGUOUS 512B per row. Source pre-swizzled (row&7)<<4, dest linear.
  auto stage = [&](int buf, int q) {
#pragma unroll
    for (int i = 0; i < 8; ++i) {
      const int row = 2 * i + (lane >> 5);
      const int sb  = ((lane & 31) * 16) ^ ((row & 7) << 4);
      GLOAD_LDS16((const char*)(Xw + (size_t)row * DD + q * 128) + sb,
                  &xlds[w][buf][i * 1024]);
    }
  };
  // W fragments for chunk q: 8 uint4 (4 steps x 2 halves), static indexing
  auto loadw = [&](uint4* wv, int q) {
#pragma unroll
    for (int s = 0; s < 4; ++s)
#pragma unroll
      for (int h = 0; h < 2; ++h)
        wv[s * 2 + h] = wtv[(((q * 4 + s) * 2 + h) << 6) + lane];
  };

  floatx4 acc0, acc1;   // cols 0-15, 16-31
#pragma unroll
  for (int j = 0; j < 4; ++j) { acc0[j] = 0.f; acc1[j] = 0.f; }

  const int arow = lane & 15;        // A-frag row
  const int koct = lane >> 4;        // A-frag k-octet (0..3)
  const int swz  = (arow & 7) << 4;

  auto compute = [&](int buf, const uint4* wv) {
    const char* base = &xlds[w][buf][0] + arow * 512;
#pragma unroll
    for (int s = 0; s < 4; ++s) {
      const int o = s * 128 + koct * 32;
      const float4 x0 = *(const float4*)(base + (o ^ swz));
      const float4 x1 = *(const float4*)(base + ((o + 16) ^ swz));
      bf16x8 xh, xm, xl;
      cvt3(x0, x1, xh, xm, xl);
      const bf16x8 b0 = __builtin_bit_cast(bf16x8, wv[s * 2]);
      const bf16x8 b1 = __builtin_bit_cast(bf16x8, wv[s * 2 + 1]);
      acc0 = __builtin_amdgcn_mfma_f32_16x16x32_bf16(xh, b0, acc0, 0, 0, 0);
      acc0 = __builtin_amdgcn_mfma_f32_16x16x32_bf16(xm, b0, acc0, 0, 0, 0);
      acc0 = __builtin_amdgcn_mfma_f32_16x16x32_bf16(xl, b0, acc0, 0, 0, 0);
      acc1 = __builtin_amdgcn_mfma_f32_16x16x32_bf16(xh, b1, acc1, 0, 0, 0);
      acc1 = __builtin_amdgcn_mfma_f32_16x16x32_bf16(xm, b1, acc1, 0, 0, 0);
      acc1 = __builtin_amdgcn_mfma_f32_16x16x32_bf16(xl, b1, acc1, 0, 0, 0);
    }
  };

  uint4 wvA[8], wvB[8];
  // wave-staggered pair walk over the 3 chunk-pairs
  int qa = 2 * (w % 3), qb = qa + 1;
  stage(0, qa); CBAR; loadw(wvA, qa); CBAR;
  stage(1, qb); CBAR; loadw(wvB, qb); CBAR;

#pragma unroll 1
  for (int p = 0; p < 3; ++p) {
    WAITV16;                          // A's stage+W landed (B's 16 in flight)
    compute(0, wvA);
    if (p < 2) {
      qa += 2; if (qa >= NCH) qa -= NCH;
      stage(0, qa); CBAR; loadw(wvA, qa); CBAR;
    }
    if (p < 2) { WAITV16; } else { WAITV0; }   // B landed
    compute(1, wvB);
    if (p < 2) {
      qb += 2; if (qb >= NCH) qb -= NCH;
      stage(1, qb); CBAR; loadw(wvB, qb); CBAR;
    }
  }

  // ---- epilogue: C layout col=lane&15, row=(lane>>4)*4+reg (m89-verified) ----
  float* cw = (float*)&xlds[w][0][0];   // reuse wave's buffer 0 (2 KB)
#pragma unroll
  for (int reg = 0; reg < 4; ++reg) {
    const int r = (lane >> 4) * 4 + reg;
    cw[r * 32 + (lane & 15)]      = acc0[reg];
    cw[r * 32 + 16 + (lane & 15)] = acc1[reg];
  }
  if (lane < 16) {
    const int r = lane;
    float cv[32];
#pragma unroll
    for (int j = 0; j < 8; ++j) {
      const float4 q4 = *(const float4*)(cw + r * 32 + j * 4);
      cv[4 * j] = q4.x; cv[4 * j + 1] = q4.y;
      cv[4 * j + 2] = q4.z; cv[4 * j + 3] = q4.w;
    }
    float g[6];
#pragma unroll
    for (int c = 0; c < 6; ++c) g[c] = cv[c] + cv[6 + c] + cv[12 + c] + gb[c];
    int best = 0; float bv = g[0];
#pragma unroll
    for (int c = 1; c < 6; ++c) { if (g[c] > bv) { bv = g[c]; best = c; } }
    float ebv[12];
#pragma unroll
    for (int i = 0; i < 12; ++i) ebv[i] = eb[i];
    float o0 = cv[18] + ebv[0], o1 = cv[19] + ebv[1];
#pragma unroll
    for (int e = 1; e < 6; ++e) {
      const bool s = (best == e);
      o0 = s ? cv[18 + 2 * e] + ebv[2 * e]     : o0;
      o1 = s ? cv[19 + 2 * e] + ebv[2 * e + 1] : o1;
    }
    ((float2*)out)[rbase + r] = make_float2(o0, o1);
  }
}

extern "C" void kernel_launch(void* const* d_in, const int* in_sizes, int n_in,
                              void* d_out, int out_size, void* d_ws, size_t ws_size,
                              hipStream_t stream) {
  (void)in_sizes; (void)n_in; (void)ws_size; (void)out_size;
  const float* X  = (const float*)d_in[0];
  const float* gw = (const float*)d_in[1];
  const float* gb = (const float*)d_in[2];
  const float* ew = (const float*)d_in[3];
  const float* eb = (const float*)d_in[4];
  float* out = (float*)d_out;
  uint4* wt = (uint4*)d_ws;   // 48 KB

  pack_w_kernel<<<WTU4 / 256 + 1, 256, 0, stream>>>(gw, ew, wt);
  HardMoE_kernel<<<BB / RPB, 256, 0, stream>>>(X, wt, gb, eb, out);
}

// Round 13
// 83.108 us; speedup vs baseline: 1.0617x; 1.0163x over previous
//
#include <hip/hip_runtime.h>

// HardMoE classifier: B=131072, D=768, E=6, L=2 == skinny GEMM 131072x30x768.
// R13: per-instruction contiguity probe. Block = ONE 32-row MFMA tile; the 4
//      waves K-SPLIT (wave w owns K16-steps s==w mod 4; partials LDS-combined).
//      Staging is block-cooperative: each global_load_lds covers 1 row x 1KB
//      FULLY CONTIGUOUS (fill-kernel footprint), 32 insts per 32KB buffer,
//      double-buffered over 3 K-chunks. Raw s_barrier + counted vmcnt(12)
//      (no __syncthreads in-loop: it would drain vmcnt). W fragments from L2
//      (R10-proven), pack kernel + fragment maps byte-identical to R9/R10.

#define BB 131072
#define DD 768
#define RPB 32              // rows per block = one MFMA tile
#define WTU (96 * 32 * 4)   // words in packed W image (48 KB)

typedef __bf16 bf16x8 __attribute__((ext_vector_type(8)));
typedef float floatx16 __attribute__((ext_vector_type(16)));
typedef unsigned short ushortx8 __attribute__((ext_vector_type(8)));

#define GLOAD_LDS16(gsrc, ldst)                                                \
  __builtin_amdgcn_global_load_lds(                                            \
      (const __attribute__((address_space(1))) void*)(gsrc),                   \
      (__attribute__((address_space(3))) void*)(ldst), 16, 0, 0)

#define WAITV12 asm volatile("s_waitcnt vmcnt(12)" ::: "memory")
#define WAITV0  asm volatile("s_waitcnt vmcnt(0)" ::: "memory")
#define SBAR                                                                   \
  {                                                                            \
    __builtin_amdgcn_s_barrier();                                              \
    __builtin_amdgcn_sched_barrier(0);                                         \
  }

__device__ __forceinline__ unsigned bf16_rne(float x) {
  const unsigned u = __builtin_bit_cast(unsigned, x);
  return (u + 0x7fffu + ((u >> 16) & 1u)) >> 16;
}

// x -> hi + mid + lo (bf16-trunc each); gate recovers full f32 product.
__device__ __forceinline__ void cvt3(const float4& a, const float4& b,
                                     bf16x8& H, bf16x8& M, bf16x8& L) {
  const float v[8] = {a.x, a.y, a.z, a.w, b.x, b.y, b.z, b.w};
  ushortx8 h, m, l;
#pragma unroll
  for (int j = 0; j < 8; ++j) {
    const float x = v[j];
    const unsigned ub = __builtin_bit_cast(unsigned, x);
    const float rm = x - __builtin_bit_cast(float, ub & 0xffff0000u);
    const unsigned mb = __builtin_bit_cast(unsigned, rm);
    const float rl = rm - __builtin_bit_cast(float, mb & 0xffff0000u);
    h[j] = (unsigned short)(ub >> 16);
    m[j] = (unsigned short)(mb >> 16);
    l[j] = (unsigned short)(__builtin_bit_cast(unsigned, rl) >> 16);
  }
  H = __builtin_bit_cast(bf16x8, h);
  M = __builtin_bit_cast(bf16x8, m);
  L = __builtin_bit_cast(bf16x8, l);
}

// ---- kernel 1: pack W image into d_ws (byte-identical to R9/R10, verified) ----
// cols 0-5 gate_hi, 6-11 gate_mid, 12-17 gate_lo, 18-29 expert(e*2+l), 30-31 0.
__global__ void pack_w_kernel(const float* __restrict__ gw,
                              const float* __restrict__ ew,
                              unsigned* __restrict__ wt) {
  const int u = blockIdx.x * 256 + threadIdx.x;
  if (u >= WTU) return;
  const int pair = u & 3;
  const int col  = (u >> 2) & 31;
  const int oct  = u >> 7;
  const int k0   = oct * 8 + pair * 2;
  unsigned val = 0;
  if (col < 18) {
    const int part = col / 6, j = col % 6;
    const float w0 = gw[j * DD + k0], w1 = gw[j * DD + k0 + 1];
    const unsigned u0 = __builtin_bit_cast(unsigned, w0);
    const unsigned u1 = __builtin_bit_cast(unsigned, w1);
    const float rm0 = w0 - __builtin_bit_cast(float, u0 & 0xffff0000u);
    const float rm1 = w1 - __builtin_bit_cast(float, u1 & 0xffff0000u);
    const unsigned m0 = __builtin_bit_cast(unsigned, rm0);
    const unsigned m1 = __builtin_bit_cast(unsigned, rm1);
    const float rl0 = rm0 - __builtin_bit_cast(float, m0 & 0xffff0000u);
    const float rl1 = rm1 - __builtin_bit_cast(float, m1 & 0xffff0000u);
    const unsigned l0 = __builtin_bit_cast(unsigned, rl0);
    const unsigned l1 = __builtin_bit_cast(unsigned, rl1);
    if (part == 0)      val = (u0 >> 16) | (u1 & 0xffff0000u);
    else if (part == 1) val = (m0 >> 16) | (m1 & 0xffff0000u);
    else                val = (l0 >> 16) | (l1 & 0xffff0000u);
  } else if (col < 30) {
    const int e = (col - 18) >> 1, l = (col - 18) & 1;
    val = bf16_rne(ew[(e * DD + k0) * 2 + l]) |
          (bf16_rne(ew[(e * DD + k0 + 1) * 2 + l]) << 16);
  }
  wt[u] = val;
}

// ---- kernel 2: main GEMM + argmax-select ----
__global__ __launch_bounds__(256, 2)
void HardMoE_kernel(const float* __restrict__ X,      // [B][768]
                    const unsigned* __restrict__ wtg, // packed W (d_ws)
                    const float* __restrict__ gb,     // [6]
                    const float* __restrict__ eb,     // [6][2]
                    float* __restrict__ out)          // [B][2]
{
  // [buf][row][1KB K-chunk], 64 KB. Content: LDS[row][p16] holds global
  // granule (p16 ^ ((row&15)<<4)) of the row's chunk (src pre-swizzle, rule 21).
  __shared__ char xbuf[2][RPB][1024];

  const int tid  = threadIdx.x;
  const int lane = tid & 63;
  const int w    = tid >> 6;
  const int mrow = lane & 31;        // A-frag row; C col
  const int koct = lane >> 5;        // A-frag k-octet
  const int rbase = blockIdx.x * RPB;
  const float* Xw = X + (size_t)rbase * DD;
  const uint4* wtv = (const uint4*)wtg;
  const int rx = (mrow & 15) << 4;   // read un-swizzle

  // stage chunk q into buf: 8 insts/wave, each ONE ROW x 1KB CONTIGUOUS.
  auto stage = [&](int buf, int q) {
#pragma unroll
    for (int i = 0; i < 8; ++i) {
      const int row = w * 8 + i;
      const int src = (lane * 16) ^ ((row & 15) << 4);
      GLOAD_LDS16((const char*)(Xw + (size_t)row * DD + q * 256) + src,
                  &xbuf[buf][row][0]);
    }
  };
  // W fragments for this wave's 4 steps of chunk q (R9 map: wtv[S*64+lane])
  auto loadw = [&](uint4* wv, int q) {
#pragma unroll
    for (int j = 0; j < 4; ++j)
      wv[j] = wtv[(q * 16 + w + 4 * j) * 64 + lane];
  };

  floatx16 acc;
#pragma unroll
  for (int j = 0; j < 16; ++j) acc[j] = 0.f;

  auto compute = [&](int buf, const uint4* wv) {
#pragma unroll
    for (int j = 0; j < 4; ++j) {
      const int o = (w + 4 * j) * 64 + koct * 32;   // in-chunk byte offset
      const char* base = &xbuf[buf][mrow][0];
      const float4 x0 = *(const float4*)(base + (o ^ rx));
      const float4 x1 = *(const float4*)(base + ((o + 16) ^ rx));
      bf16x8 xh, xm, xl;
      cvt3(x0, x1, xh, xm, xl);
      const bf16x8 bv = __builtin_bit_cast(bf16x8, wv[j]);
      acc = __builtin_amdgcn_mfma_f32_32x32x16_bf16(xh, bv, acc, 0, 0, 0);
      acc = __builtin_amdgcn_mfma_f32_32x32x16_bf16(xm, bv, acc, 0, 0, 0);
      acc = __builtin_amdgcn_mfma_f32_32x32x16_bf16(xl, bv, acc, 0, 0, 0);
    }
  };

  uint4 wvA[4], wvB[4];
  stage(0, 0); loadw(wvA, 0);        // 12 outstanding
  stage(1, 1); loadw(wvB, 1);        // 24 outstanding

  // p0
  WAITV12;                           // chunk0's 12 landed (own)
  SBAR;                              // everyone's chunk0 visible
  compute(0, wvA);
  SBAR;                              // all waves done reading buf0
  stage(0, 2); loadw(wvA, 2);        // refill buf0 (24 outstanding)
  // p1
  WAITV12;                           // chunk1 landed
  SBAR;
  compute(1, wvB);
  // p2
  WAITV0;                            // chunk2 landed
  SBAR;
  compute(0, wvA);

  // ---- epilogue: 4-way K-combine + argmax/select (R7-R10 verified maps) ----
  __syncthreads();                   // safe: pipeline drained
  float* cp = (float*)&xbuf[0][0][0];     // 4 x 4KB partial-C regions
#pragma unroll
  for (int reg = 0; reg < 16; ++reg) {
    const int r = (reg & 3) + 8 * (reg >> 2) + 4 * koct;
    *(float*)((char*)cp + w * 4096 + r * 128 +
              ((mrow * 4) ^ ((r & 7) << 4))) = acc[reg];
  }
  __syncthreads();
  if (lane < 8) {
    const int r = w * 8 + lane;
    float cv[32];
#pragma unroll
    for (int j = 0; j < 8; ++j) {
      float sx = 0.f, sy = 0.f, sz = 0.f, sw = 0.f;
#pragma unroll
      for (int p = 0; p < 4; ++p) {
        const float4 v = *(const float4*)((const char*)cp + p * 4096 + r * 128 +
                                          ((j * 16) ^ ((r & 7) << 4)));
        sx += v.x; sy += v.y; sz += v.z; sw += v.w;
      }
      cv[4 * j] = sx; cv[4 * j + 1] = sy; cv[4 * j + 2] = sz; cv[4 * j + 3] = sw;
    }
    float g[6];
#pragma unroll
    for (int c = 0; c < 6; ++c) g[c] = cv[c] + cv[6 + c] + cv[12 + c] + gb[c];
    int best = 0; float bv = g[0];
#pragma unroll
    for (int c = 1; c < 6; ++c) { if (g[c] > bv) { bv = g[c]; best = c; } }
    float ebv[12];
#pragma unroll
    for (int i = 0; i < 12; ++i) ebv[i] = eb[i];
    float o0 = cv[18] + ebv[0], o1 = cv[19] + ebv[1];
#pragma unroll
    for (int e = 1; e < 6; ++e) {
      const bool s = (best == e);
      o0 = s ? cv[18 + 2 * e] + ebv[2 * e]     : o0;
      o1 = s ? cv[19 + 2 * e] + ebv[2 * e + 1] : o1;
    }
    ((float2*)out)[rbase + r] = make_float2(o0, o1);
  }
}

extern "C" void kernel_launch(void* const* d_in, const int* in_sizes, int n_in,
                              void* d_out, int out_size, void* d_ws, size_t ws_size,
                              hipStream_t stream) {
  (void)in_sizes; (void)n_in; (void)ws_size; (void)out_size;
  const float* X  = (const float*)d_in[0];
  const float* gw = (const float*)d_in[1];
  const float* gb = (const float*)d_in[2];
  const float* ew = (const float*)d_in[3];
  const float* eb = (const float*)d_in[4];
  float* out = (float*)d_out;
  unsigned* wt = (unsigned*)d_ws;   // 48 KB

  pack_w_kernel<<<WTU / 256, 256, 0, stream>>>(gw, ew, wt);
  HardMoE_kernel<<<BB / RPB, 256, 0, stream>>>(X, wt, gb, eb, out);
}

// Round 14
// 81.130 us; speedup vs baseline: 1.0876x; 1.0244x over previous
//
#include <hip/hip_runtime.h>

// HardMoE classifier: B=131072, D=768, E=6, L=2 == skinny GEMM 131072x30x768.
// FINAL (= R10, best measured 80.7us = 5.0 TB/s sustained X read):
//  - MFMA v_mfma_f32_32x32x16_bf16; one wave = 32-row tile, all 30 output
//    cols in one accumulator. 3-way bf16 split of X and gate-W -> gate is
//    f32-exact (no argmax flips); experts exact-X x rne-bf16-W (absmax 0.0156).
//  - W image pre-packed once into d_ws (48 KB), streamed from L2 per phase.
//  - X staged via global_load_lds in channel-uniform 256B contiguous
//    per-row segments (the +35% lever found R8->R9), wave-private LDS,
//    double-buffered, zero main-loop barriers, counted vmcnt(12).
//  - Page-paired q-walk (back-to-back consecutive-q stages).
// Ledger of falsified levers: segment 512B/1KB, page pairing delta, W-in-LDS,
// W-in-VGPR, per-chunk s_load weights, occupancy 4/16, prefetch depth >2.

#define BB 131072
#define DD 768
#define RPB 128             // rows per block = 4 waves x 32
#define NSUP 12             // K supers (4 x 16-k steps each)
#define SPAN 1040           // 1024B staged + 16B pad (bank-phase shift)
#define BUFO 8320           // 8 spans per buffer
#define WREG 16640          // per-wave LDS: 2 buffers
#define WTU (96 * 32 * 4)   // uints in packed W image (48 KB)

typedef __bf16 bf16x8 __attribute__((ext_vector_type(8)));
typedef float floatx16 __attribute__((ext_vector_type(16)));
typedef unsigned short ushortx8 __attribute__((ext_vector_type(8)));

#define GLOAD_LDS16(gsrc, ldst)                                                \
  __builtin_amdgcn_global_load_lds(                                            \
      (const __attribute__((address_space(1))) void*)(gsrc),                   \
      (__attribute__((address_space(3))) void*)(ldst), 16, 0, 0)

#define WAITV12 asm volatile("s_waitcnt vmcnt(12)" ::: "memory")
#define WAITV0  asm volatile("s_waitcnt vmcnt(0)" ::: "memory")
#define CBAR    asm volatile("" ::: "memory")

__device__ __forceinline__ unsigned bf16_rne(float x) {
  const unsigned u = __builtin_bit_cast(unsigned, x);
  return (u + 0x7fffu + ((u >> 16) & 1u)) >> 16;
}

// x -> hi + mid + lo (bf16-trunc each); gate recovers full f32 product.
__device__ __forceinline__ void cvt3(const float4& a, const float4& b,
                                     bf16x8& H, bf16x8& M, bf16x8& L) {
  const float v[8] = {a.x, a.y, a.z, a.w, b.x, b.y, b.z, b.w};
  ushortx8 h, m, l;
#pragma unroll
  for (int j = 0; j < 8; ++j) {
    const float x = v[j];
    const unsigned ub = __builtin_bit_cast(unsigned, x);
    const float rm = x - __builtin_bit_cast(float, ub & 0xffff0000u);
    const unsigned mb = __builtin_bit_cast(unsigned, rm);
    const float rl = rm - __builtin_bit_cast(float, mb & 0xffff0000u);
    h[j] = (unsigned short)(ub >> 16);
    m[j] = (unsigned short)(mb >> 16);
    l[j] = (unsigned short)(__builtin_bit_cast(unsigned, rl) >> 16);
  }
  H = __builtin_bit_cast(bf16x8, h);
  M = __builtin_bit_cast(bf16x8, m);
  L = __builtin_bit_cast(bf16x8, l);
}

// ---- kernel 1: pack W image into d_ws ----
// cols 0-5 gate_hi, 6-11 gate_mid, 12-17 gate_lo, 18-29 expert(e*2+l), 30-31 0.
__global__ void pack_w_kernel(const float* __restrict__ gw,
                              const float* __restrict__ ew,
                              unsigned* __restrict__ wt) {
  const int u = blockIdx.x * 256 + threadIdx.x;
  if (u >= WTU) return;
  const int pair = u & 3;
  const int col  = (u >> 2) & 31;
  const int oct  = u >> 7;
  const int k0   = oct * 8 + pair * 2;
  unsigned val = 0;
  if (col < 18) {
    const int part = col / 6, j = col % 6;
    const float w0 = gw[j * DD + k0], w1 = gw[j * DD + k0 + 1];
    const unsigned u0 = __builtin_bit_cast(unsigned, w0);
    const unsigned u1 = __builtin_bit_cast(unsigned, w1);
    const float rm0 = w0 - __builtin_bit_cast(float, u0 & 0xffff0000u);
    const float rm1 = w1 - __builtin_bit_cast(float, u1 & 0xffff0000u);
    const unsigned m0 = __builtin_bit_cast(unsigned, rm0);
    const unsigned m1 = __builtin_bit_cast(unsigned, rm1);
    const float rl0 = rm0 - __builtin_bit_cast(float, m0 & 0xffff0000u);
    const float rl1 = rm1 - __builtin_bit_cast(float, m1 & 0xffff0000u);
    const unsigned l0 = __builtin_bit_cast(unsigned, rl0);
    const unsigned l1 = __builtin_bit_cast(unsigned, rl1);
    if (part == 0)      val = (u0 >> 16) | (u1 & 0xffff0000u);
    else if (part == 1) val = (m0 >> 16) | (m1 & 0xffff0000u);
    else                val = (l0 >> 16) | (l1 & 0xffff0000u);
  } else if (col < 30) {
    const int e = (col - 18) >> 1, l = (col - 18) & 1;
    val = bf16_rne(ew[(e * DD + k0) * 2 + l]) |
          (bf16_rne(ew[(e * DD + k0 + 1) * 2 + l]) << 16);
  }
  wt[u] = val;
}

// ---- kernel 2: main GEMM + argmax-select ----
__global__ __launch_bounds__(256, 2)
void HardMoE_kernel(const float* __restrict__ X,      // [B][768]
                    const unsigned* __restrict__ wtg, // packed W (d_ws)
                    const float* __restrict__ gb,     // [6]
                    const float* __restrict__ eb,     // [6][2]
                    float* __restrict__ out)          // [B][2]
{
  __shared__ char xlds[4 * WREG];   // 66560 B; wave-private regions

  const int tid  = threadIdx.x;
  const int lane = tid & 63;
  const int w    = tid >> 6;
  const int mrow = lane & 31;       // A row in tile; B col
  const int koct = lane >> 5;       // k-octet of the 16-k step

  const int rbase = blockIdx.x * RPB + w * 32;
  char* wb = xlds + w * WREG;
  const float* Xw = X + (size_t)rbase * DD;
  // staging: inst i covers rows 4i..4i+3, 256B contiguous per row
  const int rowoff = (lane >> 4) * DD + (lane & 15) * 4;
  // read: lane's 32B of step t lives at rdoff + t*64
  const int rdoff  = (mrow >> 2) * SPAN + (mrow & 3) * 256 + koct * 32;
  const uint4* wtv = (const uint4*)wtg;
  const int wfo = koct * 32 + mrow; // W frag idx = (q*4+t)*64 + wfo

  auto stage = [&](int bufo, int q) {
#pragma unroll
    for (int i = 0; i < 8; ++i)
      GLOAD_LDS16(Xw + i * 4 * DD + q * 64 + rowoff,
                  wb + bufo + i * SPAN + lane * 16);
  };

  floatx16 acc;
#pragma unroll
  for (int j = 0; j < 16; ++j) acc[j] = 0.f;

  uint4 wvA[4], wvB[4];

  // paired q-walk: pairs (q0+2p, q0+2p+1) mod 12; stagger keeps mod-4 phases
  // {0,3,2,1} across the 4 waves.
  int q0 = 3 * w;
  if (q0 >= NSUP) q0 -= NSUP;
  int qa = q0;
  int qb = (qa + 1 == NSUP) ? 0 : qa + 1;
  // issue order matters for vmcnt counting: [stageA(8), WA(4), stageB(8), WB(4)]
  stage(0, qa); CBAR;
#pragma unroll
  for (int t = 0; t < 4; ++t) wvA[t] = wtv[(qa * 4 + t) * 64 + wfo];
  CBAR;
  stage(BUFO, qb); CBAR;
#pragma unroll
  for (int t = 0; t < 4; ++t) wvB[t] = wtv[(qb * 4 + t) * 64 + wfo];
  CBAR;
  int qn = qb + 1; if (qn >= NSUP) qn -= NSUP;   // next pair start

#define STEP3(bufo, t, WVt)                                                    \
  {                                                                            \
    const char* p = wb + (bufo) + rdoff + (t) * 64;                            \
    const float4 x0 = *(const float4*)p;                                       \
    const float4 x1 = *(const float4*)(p + 16);                                \
    bf16x8 xh, xm, xl;                                                         \
    cvt3(x0, x1, xh, xm, xl);                                                  \
    const bf16x8 bv = __builtin_bit_cast(bf16x8, WVt);                         \
    acc = __builtin_amdgcn_mfma_f32_32x32x16_bf16(xh, bv, acc, 0, 0, 0);       \
    acc = __builtin_amdgcn_mfma_f32_32x32x16_bf16(xm, bv, acc, 0, 0, 0);       \
    acc = __builtin_amdgcn_mfma_f32_32x32x16_bf16(xl, bv, acc, 0, 0, 0);       \
  }

#pragma unroll 1
  for (int p = 0; p < 6; ++p) {
    WAITV12;                              // pair's A (stage+W) landed
    STEP3(0, 0, wvA[0]) STEP3(0, 1, wvA[1])
    STEP3(0, 2, wvA[2]) STEP3(0, 3, wvA[3])
    WAITV0;                               // pair's B landed
    STEP3(BUFO, 0, wvB[0]) STEP3(BUFO, 1, wvB[1])
    STEP3(BUFO, 2, wvB[2]) STEP3(BUFO, 3, wvB[3])
    if (p < 5) {
      // both stages back-to-back, consecutive q (one 512B page visit)
      const int nqa = qn;
      const int nqb = (nqa + 1 == NSUP) ? 0 : nqa + 1;
      stage(0, nqa); CBAR;
#pragma unroll
      for (int t = 0; t < 4; ++t) wvA[t] = wtv[(nqa * 4 + t) * 64 + wfo];
      CBAR;
      stage(BUFO, nqb); CBAR;
#pragma unroll
      for (int t = 0; t < 4; ++t) wvB[t] = wtv[(nqb * 4 + t) * 64 + wfo];
      CBAR;
      qn = nqb + 1; if (qn >= NSUP) qn -= NSUP;
    }
  }
#undef STEP3

  // ---- epilogue (R7-R12 verified): C col=lane&31, row=(reg&3)+8*(reg>>2)+4*koct
  float* cw = (float*)(xlds + w * WREG);  // reuse wave's own region
#pragma unroll
  for (int reg = 0; reg < 16; ++reg) {
    const int r = (reg & 3) + 8 * (reg >> 2) + 4 * koct;
    const int byteoff = r * 128 + ((mrow * 4) ^ ((r & 7) << 4));
    *(float*)((char*)cw + byteoff) = acc[reg];
  }
  if (lane < 32) {
    const int r = lane;
    float cv[32];
#pragma unroll
    for (int j = 0; j < 8; ++j) {
      const float4 qv = *(const float4*)((const char*)cw + r * 128 +
                                         ((j * 16) ^ ((r & 7) << 4)));
      cv[4 * j] = qv.x; cv[4 * j + 1] = qv.y;
      cv[4 * j + 2] = qv.z; cv[4 * j + 3] = qv.w;
    }
    float g[6];
#pragma unroll
    for (int c = 0; c < 6; ++c) g[c] = cv[c] + cv[6 + c] + cv[12 + c] + gb[c];
    int best = 0; float bv = g[0];
#pragma unroll
    for (int c = 1; c < 6; ++c) { if (g[c] > bv) { bv = g[c]; best = c; } }
    float ebv[12];
#pragma unroll
    for (int i = 0; i < 12; ++i) ebv[i] = eb[i];
    float o0 = cv[18] + ebv[0], o1 = cv[19] + ebv[1];
#pragma unroll
    for (int e = 1; e < 6; ++e) {
      const bool s = (best == e);
      o0 = s ? cv[18 + 2 * e] + ebv[2 * e]     : o0;
      o1 = s ? cv[19 + 2 * e] + ebv[2 * e + 1] : o1;
    }
    ((float2*)out)[rbase + r] = make_float2(o0, o1);
  }
}

extern "C" void kernel_launch(void* const* d_in, const int* in_sizes, int n_in,
                              void* d_out, int out_size, void* d_ws, size_t ws_size,
                              hipStream_t stream) {
  (void)in_sizes; (void)n_in; (void)ws_size; (void)out_size;
  const float* X  = (const float*)d_in[0];
  const float* gw = (const float*)d_in[1];
  const float* gb = (const float*)d_in[2];
  const float* ew = (const float*)d_in[3];
  const float* eb = (const float*)d_in[4];
  float* out = (float*)d_out;
  unsigned* wt = (unsigned*)d_ws;   // 48 KB

  pack_w_kernel<<<WTU / 256, 256, 0, stream>>>(gw, ew, wt);
  HardMoE_kernel<<<BB / RPB, 256, 0, stream>>>(X, wt, gb, eb, out);
}